// Round 3
// baseline (356.813 us; speedup 1.0000x reference)
//
#include <hip/hip_runtime.h>
#include <hip/hip_fp16.h>

// GRU cell, B=65536, 256 inputs, 256 hidden, fp32 in/out.
// R6: block-independence pass. R5 (dbuf + lgkm barriers + direct stores) got
// 154->136us but counters still show nothing saturated (VALU 28.5%, HBM 20%,
// MFMA ~15%): the CU's 16 waves are barrier-locked into the same phase (only
// 2 resident blocks, dispatched together) so stage/MFMA/epilogue pipes never
// overlap. Fix: MT=32, 256-thread blocks (4 waves, CPW=4, RT=2), LDS 32KB ->
// 4 INDEPENDENT blocks/CU (same 16 waves, 4 desynced phase domains, half-
// width barriers). Cost: weight L2 traffic 2x (786MB->1.57GB, L2 was ~17%
// loaded -- acceptable). Weight dbuf restructured to coltile-pair micro-steps
// (depth-1 over 32 micro-steps/pass) so VGPR stays <=128 with CPW=4.
// Retained from R5: step-0 weight prefetch issued before staging; lgkm-only
// barriers (no vmcnt drains in body); direct nontemporal epilogue-2 stores
// (R5 measured WRITE_SIZE 135MB ~= ideal, no amplification); setprio around
// MFMA clusters. launch_bounds(256,4): 4 blocks/CU -> VGPR cap 128 (R4
// lesson: hipcc 2nd arg acts as blocks/CU; for 256-thread blocks both
// interpretations agree).

#define NHID 256
#define B_ROWS 65536
#define MT 32                        // rows per block
#define RT 2                        // row tiles per wave (MT/16)
#define CPW 4                        // coltiles per wave (16 coltiles / 4 waves)
#define GATE_STRIDE (16 * 16 * 64 * 8)   // halves per packed gate

typedef _Float16 half8 __attribute__((ext_vector_type(8)));
typedef _Float16 half4_t __attribute__((ext_vector_type(4)));
typedef _Float16 half2_t __attribute__((ext_vector_type(2)));
typedef float floatx4 __attribute__((ext_vector_type(4)));

// LDS layout for lx/lh: row-major [MT][256] halves, 8-half-chunk XOR swizzle
__device__ __forceinline__ int lidx(int m, int c) {
    return m * 256 + ((((c >> 3) ^ (m & 7)) << 3)) + (c & 7);
}

// Workgroup barrier that waits only on LDS ops (lgkmcnt), NOT vmcnt -- keeps
// prefetched global loads in flight across phase boundaries. All cross-wave
// hazards at these points are LDS-only, so this is sufficient.
__device__ __forceinline__ void barrier_lgkm() {
    __builtin_amdgcn_sched_barrier(0);
    asm volatile("s_waitcnt lgkmcnt(0)" ::: "memory");
    __builtin_amdgcn_s_barrier();
    __builtin_amdgcn_sched_barrier(0);
}

// ---------- weight packing: B-fragment layout for mfma_f32_16x16x32_f16 ----
// frag (gate g, coltile ct, ktile s): lane holds B[k=s*32+(lane>>4)*8+j][n=ct*16+(lane&15)]
__global__ __launch_bounds__(256) void pack_weights_kernel(
    const float* __restrict__ Wz, const float* __restrict__ Uz,
    const float* __restrict__ Wr, const float* __restrict__ Ur,
    const float* __restrict__ Wh, const float* __restrict__ Uh,
    _Float16* __restrict__ packed)
{
    int tid = blockIdx.x * blockDim.x + threadIdx.x;  // 0..49151
    int lane = tid & 63;
    int s    = (tid >> 6) & 15;
    int ct   = (tid >> 10) & 15;
    int g    = tid >> 14;  // 0:z 1:r 2:h
    const float* W = (g == 0) ? Wz : (g == 1) ? Wr : Wh;
    const float* U = (g == 0) ? Uz : (g == 1) ? Ur : Uh;
    int n  = ct * 16 + (lane & 15);
    int k0 = s * 32 + (lane >> 4) * 8;
    half8 v;
#pragma unroll
    for (int j = 0; j < 8; ++j) {
        int k = k0 + j;
        float f = (k < 256) ? W[k * 256 + n] : U[(k - 256) * 256 + n];
        v[j] = (_Float16)f;
    }
    *reinterpret_cast<half8*>(packed + (size_t)tid * 8) = v;
}

// fragment load for (gate base, coltile ct, ktile s)
#define WFRAG(base, ct, s) \
    (*reinterpret_cast<const half8*>((base) + (size_t)((((ct) * 16 + (s)) * 64 + lane) * 8)))

// ---------- main fused GRU kernel ----------
__global__ __launch_bounds__(256, 4) void gru_main_kernel(
    const float* __restrict__ x, const float* __restrict__ h,
    const _Float16* __restrict__ wpack,
    const float* __restrict__ bz, const float* __restrict__ br,
    const float* __restrict__ bh,
    float* __restrict__ out)
{
    // 32 KB: lx[32*256] + lh[32*256] halves -> 4 blocks/CU (128 KB of 160 KB)
    __shared__ __align__(16) _Float16 lsm[MT * 256 * 2];
    _Float16* lx = lsm;
    _Float16* lh = lsm + MT * 256;

    const int tid  = threadIdx.x;
    const int lane = tid & 63;
    const int wave = tid >> 6;        // 0..3, owns coltiles wave*4 .. wave*4+3
    const int row0 = blockIdx.x * MT;
    const int m_lo = lane & 15;
    const int quad = lane >> 4;
    const int mx   = m_lo & 7;
    const int ct0  = wave * CPW;

    const _Float16* wz = wpack;
    const _Float16* wr = wpack + GATE_STRIDE;
    const _Float16* wh = wpack + 2 * GATE_STRIDE;

    // ---- prefetch micro-step 0 weight frags (coltile pair 0): in flight
    //      under the staging HBM loads and across the lgkm-only barrier ----
    // dbuf indexed by pair parity p: consume [p], load [p^1].
    half8 wzb[2][2], wrb[2][2];
    wzb[0][0] = WFRAG(wz, ct0 + 0, 0);
    wzb[0][1] = WFRAG(wz, ct0 + 1, 0);
    wrb[0][0] = WFRAG(wr, ct0 + 0, 0);
    wrb[0][1] = WFRAG(wr, ct0 + 1, 0);

    // ---- stage x, h -> LDS fp16 (16 outstanding 16B loads/thread) ----
    {
        const float4* xv = reinterpret_cast<const float4*>(x + (size_t)row0 * NHID);
        const float4* hv = reinterpret_cast<const float4*>(h + (size_t)row0 * NHID);
#pragma unroll
        for (int it = 0; it < (MT * 64) / 256; ++it) {
            int i = it * 256 + tid;
            int m = i >> 6;
            int c = (i & 63) * 4;
            float4 a = xv[i];
            float4 b = hv[i];
            half4_t va = { (_Float16)a.x, (_Float16)a.y, (_Float16)a.z, (_Float16)a.w };
            half4_t vb = { (_Float16)b.x, (_Float16)b.y, (_Float16)b.z, (_Float16)b.w };
            *reinterpret_cast<half4_t*>(&lx[lidx(m, c)]) = va;
            *reinterpret_cast<half4_t*>(&lh[lidx(m, c)]) = vb;
        }
    }
    barrier_lgkm();

    // packed (z*h, 1-z) per output element, fp16x2 (32 VGPRs, live pass2 only)
    half2_t zpk[CPW][RT][4];

    // ---- pass 1: Sz = [x|h]@[Wz;Uz], Sr = [x|h]@[Wr;Ur]  (K=512) ----
    // 32 micro-steps (s,p): each = {prefetch next pair's 4 frags, 8 MFMAs}.
    floatx4 accz[CPW][RT];
    floatx4 accr[CPW][RT];
#pragma unroll
    for (int c = 0; c < CPW; ++c)
#pragma unroll
        for (int rt = 0; rt < RT; ++rt) {
            accz[c][rt] = (floatx4){0.f, 0.f, 0.f, 0.f};
            accr[c][rt] = (floatx4){0.f, 0.f, 0.f, 0.f};
        }

#pragma unroll
    for (int s = 0; s < 16; ++s) {
        const _Float16* asrc = (s < 8) ? lx : lh;
        const int kcx = (((s & 7) * 4 + quad) ^ mx) << 3;
        half8 af[RT];
#pragma unroll
        for (int rt = 0; rt < RT; ++rt)
            af[rt] = *reinterpret_cast<const half8*>(&asrc[(rt * 16 + m_lo) * 256 + kcx]);
#pragma unroll
        for (int p = 0; p < 2; ++p) {
            const int u = s * 2 + p;               // micro-step 0..31
            if (u < 31) {
                const int ns = (p == 1) ? s + 1 : s;
                const int nc = ct0 + (p ^ 1) * 2;  // next pair's coltile base
                wzb[p ^ 1][0] = WFRAG(wz, nc + 0, ns);
                wzb[p ^ 1][1] = WFRAG(wz, nc + 1, ns);
                wrb[p ^ 1][0] = WFRAG(wr, nc + 0, ns);
                wrb[p ^ 1][1] = WFRAG(wr, nc + 1, ns);
            }
            __builtin_amdgcn_s_setprio(1);
#pragma unroll
            for (int q = 0; q < 2; ++q) {
                const int c = p * 2 + q;
#pragma unroll
                for (int rt = 0; rt < RT; ++rt) {
                    accz[c][rt] = __builtin_amdgcn_mfma_f32_16x16x32_f16(af[rt], wzb[p][q], accz[c][rt], 0, 0, 0);
                    accr[c][rt] = __builtin_amdgcn_mfma_f32_16x16x32_f16(af[rt], wrb[p][q], accr[c][rt], 0, 0, 0);
                }
            }
            __builtin_amdgcn_s_setprio(0);
        }
    }

    // ---- prefetch pass-2 micro-step-0 weights + all biases: issued before
    //      the barrier, stay in flight through epilogue 1 ----
    half8 whb[2][2];
    whb[0][0] = WFRAG(wh, ct0 + 0, 0);
    whb[0][1] = WFRAG(wh, ct0 + 1, 0);
    float bzv[CPW], brv[CPW], bhv[CPW];
#pragma unroll
    for (int c = 0; c < CPW; ++c) {
        const int col = (ct0 + c) * 16 + m_lo;
        bzv[c] = bz[col];
        brv[c] = br[col];
        bhv[c] = bh[col];
    }

    barrier_lgkm();  // all waves done reading lh before overwriting with r*h

    // ---- epilogue 1: z, r; lh <- r*h; zpk <- (fp16)(z*h, 1-z) ----
    // C layout: col(tile) = lane&15, row(tile) = quad*4 + reg
#pragma unroll
    for (int c = 0; c < CPW; ++c) {
        const int col = (ct0 + c) * 16 + m_lo;
#pragma unroll
        for (int rt = 0; rt < RT; ++rt) {
#pragma unroll
            for (int e = 0; e < 4; ++e) {
                const int row = rt * 16 + quad * 4 + e;
                float sz = accz[c][rt][e] + bzv[c];
                float sr = accr[c][rt][e] + brv[c];
                float zv = 1.f / (1.f + __expf(-sz));
                float rv = 1.f / (1.f + __expf(-sr));
                const int li = lidx(row, col);
                float hval = (float)lh[li];
                lh[li] = (_Float16)(rv * hval);
                zpk[c][rt][e] = half2_t{ (_Float16)(zv * hval), (_Float16)(1.f - zv) };
            }
        }
    }

    barrier_lgkm();  // r*h visible to all waves

    // ---- pass 2: Sh = [x|r*h]@[Wh;Uh]  (K=512), 32 micro-steps ----
    floatx4 acch[CPW][RT];
#pragma unroll
    for (int c = 0; c < CPW; ++c)
#pragma unroll
        for (int rt = 0; rt < RT; ++rt)
            acch[c][rt] = (floatx4){0.f, 0.f, 0.f, 0.f};

#pragma unroll
    for (int s = 0; s < 16; ++s) {
        const _Float16* asrc = (s < 8) ? lx : lh;
        const int kcx = (((s & 7) * 4 + quad) ^ mx) << 3;
        half8 af[RT];
#pragma unroll
        for (int rt = 0; rt < RT; ++rt)
            af[rt] = *reinterpret_cast<const half8*>(&asrc[(rt * 16 + m_lo) * 256 + kcx]);
#pragma unroll
        for (int p = 0; p < 2; ++p) {
            const int u = s * 2 + p;
            if (u < 31) {
                const int ns = (p == 1) ? s + 1 : s;
                const int nc = ct0 + (p ^ 1) * 2;
                whb[p ^ 1][0] = WFRAG(wh, nc + 0, ns);
                whb[p ^ 1][1] = WFRAG(wh, nc + 1, ns);
            }
            __builtin_amdgcn_s_setprio(1);
#pragma unroll
            for (int q = 0; q < 2; ++q) {
                const int c = p * 2 + q;
#pragma unroll
                for (int rt = 0; rt < RT; ++rt)
                    acch[c][rt] = __builtin_amdgcn_mfma_f32_16x16x32_f16(af[rt], whb[p][q], acch[c][rt], 0, 0, 0);
            }
            __builtin_amdgcn_s_setprio(0);
        }
    }

    // ---- epilogue 2: h_t = z*h + (1-z)*tanh(Sh+bh), direct global stores ----
    // No barrier: nothing after this touches LDS. 16-lane groups write
    // contiguous 64 B segments (R5 measured WRITE_SIZE ~= ideal, no
    // amplification).
    const size_t OUT2 = (size_t)B_ROWS * NHID;
#pragma unroll
    for (int c = 0; c < CPW; ++c) {
        const int col = (ct0 + c) * 16 + m_lo;
#pragma unroll
        for (int rt = 0; rt < RT; ++rt) {
#pragma unroll
            for (int e = 0; e < 4; ++e) {
                const int row = rt * 16 + quad * 4 + e;
                float sh = acch[c][rt][e] + bhv[c];
                float e2 = __expf(2.f * sh);
                float hh = 1.f - 2.f / (e2 + 1.f);  // tanh
                float zh  = (float)zpk[c][rt][e][0];
                float omz = (float)zpk[c][rt][e][1];
                float ht  = zh + omz * hh;
                size_t idx = (size_t)(row0 + row) * NHID + col;
                __builtin_nontemporal_store(ht, &out[idx]);
                __builtin_nontemporal_store(ht, &out[OUT2 + idx]);
            }
        }
    }
}

extern "C" void kernel_launch(void* const* d_in, const int* in_sizes, int n_in,
                              void* d_out, int out_size, void* d_ws, size_t ws_size,
                              hipStream_t stream) {
    (void)in_sizes; (void)n_in; (void)out_size; (void)ws_size;
    const float* x  = (const float*)d_in[0];
    const float* h  = (const float*)d_in[1];
    const float* Wz = (const float*)d_in[2];
    const float* Uz = (const float*)d_in[3];
    const float* bz = (const float*)d_in[4];
    const float* Wr = (const float*)d_in[5];
    const float* Ur = (const float*)d_in[6];
    const float* br = (const float*)d_in[7];
    const float* Wh = (const float*)d_in[8];
    const float* Uh = (const float*)d_in[9];
    const float* bh = (const float*)d_in[10];
    float* out = (float*)d_out;
    _Float16* wpack = (_Float16*)d_ws;  // 3*512*256*2 = 768 KB

    pack_weights_kernel<<<192, 256, 0, stream>>>(Wz, Uz, Wr, Ur, Wh, Uh, wpack);
    gru_main_kernel<<<B_ROWS / MT, 256, 0, stream>>>(x, h, wpack, bz, br, bh, out);
}

// Round 4
// 354.750 us; speedup vs baseline: 1.0058x; 1.0058x over previous
//
#include <hip/hip_runtime.h>
#include <hip/hip_fp16.h>

// GRU cell, B=65536, 256 inputs, 256 hidden, fp32 in/out.
// R7 = R6 with the register cap set correctly. Three rounds of data pin the
// hipcc launch_bounds mapping: (512,4)->cap 64, (256,4)->cap 64, (512,2)->
// cap 128, i.e. effective min-waves/EU = 2 * arg2 (cap = 512/min_waves).
// R6's (256,4) therefore forced 64 VGPR onto a ~120-reg structure -> spills
// (FETCH +58MB, WRITE +152MB) and 186us; the 4-blocks/CU desync experiment
// never ran (though Occupancy 35% confirms 4 blocks WERE resident).
// R7 uses the unambiguous LLVM attribute amdgpu_waves_per_eu(4): min 4
// waves/SIMD -> VGPR cap 512/4 = 128. Structure byte-identical to R6:
// MT=32, 256-thread blocks (4 waves, CPW=4, RT=2), 32KB LDS -> 4 independent
// blocks/CU (4 desynced phase domains vs R5's 2), coltile-pair micro-step
// weight dbuf, lgkm-only barriers, step-0 prefetch before staging, direct
// nontemporal epilogue-2 stores, setprio around MFMA clusters.

#define NHID 256
#define B_ROWS 65536
#define MT 32                        // rows per block
#define RT 2                        // row tiles per wave (MT/16)
#define CPW 4                        // coltiles per wave (16 coltiles / 4 waves)
#define GATE_STRIDE (16 * 16 * 64 * 8)   // halves per packed gate

typedef _Float16 half8 __attribute__((ext_vector_type(8)));
typedef _Float16 half4_t __attribute__((ext_vector_type(4)));
typedef _Float16 half2_t __attribute__((ext_vector_type(2)));
typedef float floatx4 __attribute__((ext_vector_type(4)));

// LDS layout for lx/lh: row-major [MT][256] halves, 8-half-chunk XOR swizzle
__device__ __forceinline__ int lidx(int m, int c) {
    return m * 256 + ((((c >> 3) ^ (m & 7)) << 3)) + (c & 7);
}

// Workgroup barrier that waits only on LDS ops (lgkmcnt), NOT vmcnt -- keeps
// prefetched global loads in flight across phase boundaries. All cross-wave
// hazards at these points are LDS-only, so this is sufficient.
__device__ __forceinline__ void barrier_lgkm() {
    __builtin_amdgcn_sched_barrier(0);
    asm volatile("s_waitcnt lgkmcnt(0)" ::: "memory");
    __builtin_amdgcn_s_barrier();
    __builtin_amdgcn_sched_barrier(0);
}

// ---------- weight packing: B-fragment layout for mfma_f32_16x16x32_f16 ----
// frag (gate g, coltile ct, ktile s): lane holds B[k=s*32+(lane>>4)*8+j][n=ct*16+(lane&15)]
__global__ __launch_bounds__(256) void pack_weights_kernel(
    const float* __restrict__ Wz, const float* __restrict__ Uz,
    const float* __restrict__ Wr, const float* __restrict__ Ur,
    const float* __restrict__ Wh, const float* __restrict__ Uh,
    _Float16* __restrict__ packed)
{
    int tid = blockIdx.x * blockDim.x + threadIdx.x;  // 0..49151
    int lane = tid & 63;
    int s    = (tid >> 6) & 15;
    int ct   = (tid >> 10) & 15;
    int g    = tid >> 14;  // 0:z 1:r 2:h
    const float* W = (g == 0) ? Wz : (g == 1) ? Wr : Wh;
    const float* U = (g == 0) ? Uz : (g == 1) ? Ur : Uh;
    int n  = ct * 16 + (lane & 15);
    int k0 = s * 32 + (lane >> 4) * 8;
    half8 v;
#pragma unroll
    for (int j = 0; j < 8; ++j) {
        int k = k0 + j;
        float f = (k < 256) ? W[k * 256 + n] : U[(k - 256) * 256 + n];
        v[j] = (_Float16)f;
    }
    *reinterpret_cast<half8*>(packed + (size_t)tid * 8) = v;
}

// fragment load for (gate base, coltile ct, ktile s)
#define WFRAG(base, ct, s) \
    (*reinterpret_cast<const half8*>((base) + (size_t)((((ct) * 16 + (s)) * 64 + lane) * 8)))

// ---------- main fused GRU kernel ----------
__global__ __launch_bounds__(256) __attribute__((amdgpu_waves_per_eu(4)))
void gru_main_kernel(
    const float* __restrict__ x, const float* __restrict__ h,
    const _Float16* __restrict__ wpack,
    const float* __restrict__ bz, const float* __restrict__ br,
    const float* __restrict__ bh,
    float* __restrict__ out)
{
    // 32 KB: lx[32*256] + lh[32*256] halves -> 4 blocks/CU (128 KB of 160 KB)
    __shared__ __align__(16) _Float16 lsm[MT * 256 * 2];
    _Float16* lx = lsm;
    _Float16* lh = lsm + MT * 256;

    const int tid  = threadIdx.x;
    const int lane = tid & 63;
    const int wave = tid >> 6;        // 0..3, owns coltiles wave*4 .. wave*4+3
    const int row0 = blockIdx.x * MT;
    const int m_lo = lane & 15;
    const int quad = lane >> 4;
    const int mx   = m_lo & 7;
    const int ct0  = wave * CPW;

    const _Float16* wz = wpack;
    const _Float16* wr = wpack + GATE_STRIDE;
    const _Float16* wh = wpack + 2 * GATE_STRIDE;

    // ---- prefetch micro-step 0 weight frags (coltile pair 0): in flight
    //      under the staging HBM loads and across the lgkm-only barrier ----
    // dbuf indexed by pair parity p: consume [p], load [p^1].
    half8 wzb[2][2], wrb[2][2];
    wzb[0][0] = WFRAG(wz, ct0 + 0, 0);
    wzb[0][1] = WFRAG(wz, ct0 + 1, 0);
    wrb[0][0] = WFRAG(wr, ct0 + 0, 0);
    wrb[0][1] = WFRAG(wr, ct0 + 1, 0);

    // ---- stage x, h -> LDS fp16 (16 outstanding 16B loads/thread) ----
    {
        const float4* xv = reinterpret_cast<const float4*>(x + (size_t)row0 * NHID);
        const float4* hv = reinterpret_cast<const float4*>(h + (size_t)row0 * NHID);
#pragma unroll
        for (int it = 0; it < (MT * 64) / 256; ++it) {
            int i = it * 256 + tid;
            int m = i >> 6;
            int c = (i & 63) * 4;
            float4 a = xv[i];
            float4 b = hv[i];
            half4_t va = { (_Float16)a.x, (_Float16)a.y, (_Float16)a.z, (_Float16)a.w };
            half4_t vb = { (_Float16)b.x, (_Float16)b.y, (_Float16)b.z, (_Float16)b.w };
            *reinterpret_cast<half4_t*>(&lx[lidx(m, c)]) = va;
            *reinterpret_cast<half4_t*>(&lh[lidx(m, c)]) = vb;
        }
    }
    barrier_lgkm();

    // packed (z*h, 1-z) per output element, fp16x2 (16 VGPRs, live pass2 only)
    half2_t zpk[CPW][RT][4];

    // ---- pass 1: Sz = [x|h]@[Wz;Uz], Sr = [x|h]@[Wr;Ur]  (K=512) ----
    // 32 micro-steps (s,p): each = {prefetch next pair's 4 frags, 8 MFMAs}.
    floatx4 accz[CPW][RT];
    floatx4 accr[CPW][RT];
#pragma unroll
    for (int c = 0; c < CPW; ++c)
#pragma unroll
        for (int rt = 0; rt < RT; ++rt) {
            accz[c][rt] = (floatx4){0.f, 0.f, 0.f, 0.f};
            accr[c][rt] = (floatx4){0.f, 0.f, 0.f, 0.f};
        }

#pragma unroll
    for (int s = 0; s < 16; ++s) {
        const _Float16* asrc = (s < 8) ? lx : lh;
        const int kcx = (((s & 7) * 4 + quad) ^ mx) << 3;
        half8 af[RT];
#pragma unroll
        for (int rt = 0; rt < RT; ++rt)
            af[rt] = *reinterpret_cast<const half8*>(&asrc[(rt * 16 + m_lo) * 256 + kcx]);
#pragma unroll
        for (int p = 0; p < 2; ++p) {
            const int u = s * 2 + p;               // micro-step 0..31
            if (u < 31) {
                const int ns = (p == 1) ? s + 1 : s;
                const int nc = ct0 + (p ^ 1) * 2;  // next pair's coltile base
                wzb[p ^ 1][0] = WFRAG(wz, nc + 0, ns);
                wzb[p ^ 1][1] = WFRAG(wz, nc + 1, ns);
                wrb[p ^ 1][0] = WFRAG(wr, nc + 0, ns);
                wrb[p ^ 1][1] = WFRAG(wr, nc + 1, ns);
            }
            __builtin_amdgcn_s_setprio(1);
#pragma unroll
            for (int q = 0; q < 2; ++q) {
                const int c = p * 2 + q;
#pragma unroll
                for (int rt = 0; rt < RT; ++rt) {
                    accz[c][rt] = __builtin_amdgcn_mfma_f32_16x16x32_f16(af[rt], wzb[p][q], accz[c][rt], 0, 0, 0);
                    accr[c][rt] = __builtin_amdgcn_mfma_f32_16x16x32_f16(af[rt], wrb[p][q], accr[c][rt], 0, 0, 0);
                }
            }
            __builtin_amdgcn_s_setprio(0);
        }
    }

    // ---- prefetch pass-2 micro-step-0 weights + all biases: issued before
    //      the barrier, stay in flight through epilogue 1 ----
    half8 whb[2][2];
    whb[0][0] = WFRAG(wh, ct0 + 0, 0);
    whb[0][1] = WFRAG(wh, ct0 + 1, 0);
    float bzv[CPW], brv[CPW], bhv[CPW];
#pragma unroll
    for (int c = 0; c < CPW; ++c) {
        const int col = (ct0 + c) * 16 + m_lo;
        bzv[c] = bz[col];
        brv[c] = br[col];
        bhv[c] = bh[col];
    }

    barrier_lgkm();  // all waves done reading lh before overwriting with r*h

    // ---- epilogue 1: z, r; lh <- r*h; zpk <- (fp16)(z*h, 1-z) ----
    // C layout: col(tile) = lane&15, row(tile) = quad*4 + reg
#pragma unroll
    for (int c = 0; c < CPW; ++c) {
        const int col = (ct0 + c) * 16 + m_lo;
#pragma unroll
        for (int rt = 0; rt < RT; ++rt) {
#pragma unroll
            for (int e = 0; e < 4; ++e) {
                const int row = rt * 16 + quad * 4 + e;
                float sz = accz[c][rt][e] + bzv[c];
                float sr = accr[c][rt][e] + brv[c];
                float zv = 1.f / (1.f + __expf(-sz));
                float rv = 1.f / (1.f + __expf(-sr));
                const int li = lidx(row, col);
                float hval = (float)lh[li];
                lh[li] = (_Float16)(rv * hval);
                zpk[c][rt][e] = half2_t{ (_Float16)(zv * hval), (_Float16)(1.f - zv) };
            }
        }
    }

    barrier_lgkm();  // r*h visible to all waves

    // ---- pass 2: Sh = [x|r*h]@[Wh;Uh]  (K=512), 32 micro-steps ----
    floatx4 acch[CPW][RT];
#pragma unroll
    for (int c = 0; c < CPW; ++c)
#pragma unroll
        for (int rt = 0; rt < RT; ++rt)
            acch[c][rt] = (floatx4){0.f, 0.f, 0.f, 0.f};

#pragma unroll
    for (int s = 0; s < 16; ++s) {
        const _Float16* asrc = (s < 8) ? lx : lh;
        const int kcx = (((s & 7) * 4 + quad) ^ mx) << 3;
        half8 af[RT];
#pragma unroll
        for (int rt = 0; rt < RT; ++rt)
            af[rt] = *reinterpret_cast<const half8*>(&asrc[(rt * 16 + m_lo) * 256 + kcx]);
#pragma unroll
        for (int p = 0; p < 2; ++p) {
            const int u = s * 2 + p;
            if (u < 31) {
                const int ns = (p == 1) ? s + 1 : s;
                const int nc = ct0 + (p ^ 1) * 2;
                whb[p ^ 1][0] = WFRAG(wh, nc + 0, ns);
                whb[p ^ 1][1] = WFRAG(wh, nc + 1, ns);
            }
            __builtin_amdgcn_s_setprio(1);
#pragma unroll
            for (int q = 0; q < 2; ++q) {
                const int c = p * 2 + q;
#pragma unroll
                for (int rt = 0; rt < RT; ++rt)
                    acch[c][rt] = __builtin_amdgcn_mfma_f32_16x16x32_f16(af[rt], whb[p][q], acch[c][rt], 0, 0, 0);
            }
            __builtin_amdgcn_s_setprio(0);
        }
    }

    // ---- epilogue 2: h_t = z*h + (1-z)*tanh(Sh+bh), direct global stores ----
    // No barrier: nothing after this touches LDS. 16-lane groups write
    // contiguous 64 B segments (R5 measured WRITE_SIZE ~= ideal, no
    // amplification).
    const size_t OUT2 = (size_t)B_ROWS * NHID;
#pragma unroll
    for (int c = 0; c < CPW; ++c) {
        const int col = (ct0 + c) * 16 + m_lo;
#pragma unroll
        for (int rt = 0; rt < RT; ++rt) {
#pragma unroll
            for (int e = 0; e < 4; ++e) {
                const int row = rt * 16 + quad * 4 + e;
                float sh = acch[c][rt][e] + bhv[c];
                float e2 = __expf(2.f * sh);
                float hh = 1.f - 2.f / (e2 + 1.f);  // tanh
                float zh  = (float)zpk[c][rt][e][0];
                float omz = (float)zpk[c][rt][e][1];
                float ht  = zh + omz * hh;
                size_t idx = (size_t)(row0 + row) * NHID + col;
                __builtin_nontemporal_store(ht, &out[idx]);
                __builtin_nontemporal_store(ht, &out[OUT2 + idx]);
            }
        }
    }
}

extern "C" void kernel_launch(void* const* d_in, const int* in_sizes, int n_in,
                              void* d_out, int out_size, void* d_ws, size_t ws_size,
                              hipStream_t stream) {
    (void)in_sizes; (void)n_in; (void)out_size; (void)ws_size;
    const float* x  = (const float*)d_in[0];
    const float* h  = (const float*)d_in[1];
    const float* Wz = (const float*)d_in[2];
    const float* Uz = (const float*)d_in[3];
    const float* bz = (const float*)d_in[4];
    const float* Wr = (const float*)d_in[5];
    const float* Ur = (const float*)d_in[6];
    const float* br = (const float*)d_in[7];
    const float* Wh = (const float*)d_in[8];
    const float* Uh = (const float*)d_in[9];
    const float* bh = (const float*)d_in[10];
    float* out = (float*)d_out;
    _Float16* wpack = (_Float16*)d_ws;  // 3*512*256*2 = 768 KB

    pack_weights_kernel<<<192, 256, 0, stream>>>(Wz, Uz, Wr, Ur, Wh, Uh, wpack);
    gru_main_kernel<<<B_ROWS / MT, 256, 0, stream>>>(x, h, wpack, bz, br, bh, out);
}

// Round 5
// 312.426 us; speedup vs baseline: 1.1421x; 1.1355x over previous
//
#include <hip/hip_runtime.h>
#include <hip/hip_fp16.h>

// GRU cell, B=65536, 256 inputs, 256 hidden, fp32 in/out.
// R8: third attempt at the 4-blocks/CU desync experiment, register cap set
// via the MEASURED launch-bounds rule. Data: (512,4)->cap 64, (256,4)->cap
// 64, (512,2)->cap 128 => effective min-waves/EU = 2*arg2, cap = 512/(2*arg2)
// INDEPENDENT of block size. R7's amdgpu_waves_per_eu(4) was ignored (still
// 64 VGPR + spills). So: __launch_bounds__(256, 2) -> min-waves 4 -> cap 128.
// Gate for a clean run: VGPR 96-128, FETCH ~78-95MB, WRITE ~135MB.
// Theory (from R5's clean counters): phases serialize -- 34us HBM staging +
// 25us MFMA + ~30us VALU/TRANS epilogues ~= the 136us measured. 4 independent
// 256-thread blocks/CU (vs 2 synced 512-thread blocks) desync the phases so
// stage/MFMA/epilogue overlap across blocks (m114: MFMA+VALU pipes co-issue).
// New in R8 vs R6/R7 (besides the bounds fix): the epilogue-1 -> pass-2
// barrier moved INSIDE pass 2 between s=7 and s=8 -- pass-2 s<8 reads only
// lx, which epilogue-1 never writes, so each wave runs epilogue-1 straight
// into 8 MFMA steps with no block-wide stop (sigmoid/TRANS burst hides under
// other waves' MFMAs).
// Retained: MT=32, 4 waves, CPW=4, RT=2, 32KB LDS; coltile-pair micro-step
// weight dbuf; lgkm-only barriers (no vmcnt drains in body); step-0 weight
// prefetch before staging; direct nontemporal epilogue-2 stores; setprio
// around MFMA clusters.

#define NHID 256
#define B_ROWS 65536
#define MT 32                        // rows per block
#define RT 2                        // row tiles per wave (MT/16)
#define CPW 4                        // coltiles per wave (16 coltiles / 4 waves)
#define GATE_STRIDE (16 * 16 * 64 * 8)   // halves per packed gate

typedef _Float16 half8 __attribute__((ext_vector_type(8)));
typedef _Float16 half4_t __attribute__((ext_vector_type(4)));
typedef _Float16 half2_t __attribute__((ext_vector_type(2)));
typedef float floatx4 __attribute__((ext_vector_type(4)));

// LDS layout for lx/lh: row-major [MT][256] halves, 8-half-chunk XOR swizzle
__device__ __forceinline__ int lidx(int m, int c) {
    return m * 256 + ((((c >> 3) ^ (m & 7)) << 3)) + (c & 7);
}

// Workgroup barrier that waits only on LDS ops (lgkmcnt), NOT vmcnt -- keeps
// prefetched global loads in flight across phase boundaries. All cross-wave
// hazards at these points are LDS-only, so this is sufficient.
__device__ __forceinline__ void barrier_lgkm() {
    __builtin_amdgcn_sched_barrier(0);
    asm volatile("s_waitcnt lgkmcnt(0)" ::: "memory");
    __builtin_amdgcn_s_barrier();
    __builtin_amdgcn_sched_barrier(0);
}

// ---------- weight packing: B-fragment layout for mfma_f32_16x16x32_f16 ----
// frag (gate g, coltile ct, ktile s): lane holds B[k=s*32+(lane>>4)*8+j][n=ct*16+(lane&15)]
__global__ __launch_bounds__(256) void pack_weights_kernel(
    const float* __restrict__ Wz, const float* __restrict__ Uz,
    const float* __restrict__ Wr, const float* __restrict__ Ur,
    const float* __restrict__ Wh, const float* __restrict__ Uh,
    _Float16* __restrict__ packed)
{
    int tid = blockIdx.x * blockDim.x + threadIdx.x;  // 0..49151
    int lane = tid & 63;
    int s    = (tid >> 6) & 15;
    int ct   = (tid >> 10) & 15;
    int g    = tid >> 14;  // 0:z 1:r 2:h
    const float* W = (g == 0) ? Wz : (g == 1) ? Wr : Wh;
    const float* U = (g == 0) ? Uz : (g == 1) ? Ur : Uh;
    int n  = ct * 16 + (lane & 15);
    int k0 = s * 32 + (lane >> 4) * 8;
    half8 v;
#pragma unroll
    for (int j = 0; j < 8; ++j) {
        int k = k0 + j;
        float f = (k < 256) ? W[k * 256 + n] : U[(k - 256) * 256 + n];
        v[j] = (_Float16)f;
    }
    *reinterpret_cast<half8*>(packed + (size_t)tid * 8) = v;
}

// fragment load for (gate base, coltile ct, ktile s)
#define WFRAG(base, ct, s) \
    (*reinterpret_cast<const half8*>((base) + (size_t)((((ct) * 16 + (s)) * 64 + lane) * 8)))

// ---------- main fused GRU kernel ----------
__global__ __launch_bounds__(256, 2) void gru_main_kernel(
    const float* __restrict__ x, const float* __restrict__ h,
    const _Float16* __restrict__ wpack,
    const float* __restrict__ bz, const float* __restrict__ br,
    const float* __restrict__ bh,
    float* __restrict__ out)
{
    // 32 KB: lx[32*256] + lh[32*256] halves -> 4 blocks/CU (128 KB of 160 KB)
    __shared__ __align__(16) _Float16 lsm[MT * 256 * 2];
    _Float16* lx = lsm;
    _Float16* lh = lsm + MT * 256;

    const int tid  = threadIdx.x;
    const int lane = tid & 63;
    const int wave = tid >> 6;        // 0..3, owns coltiles wave*4 .. wave*4+3
    const int row0 = blockIdx.x * MT;
    const int m_lo = lane & 15;
    const int quad = lane >> 4;
    const int mx   = m_lo & 7;
    const int ct0  = wave * CPW;

    const _Float16* wz = wpack;
    const _Float16* wr = wpack + GATE_STRIDE;
    const _Float16* wh = wpack + 2 * GATE_STRIDE;

    // ---- prefetch micro-step 0 weight frags (coltile pair 0): in flight
    //      under the staging HBM loads and across the lgkm-only barrier ----
    // dbuf indexed by pair parity p: consume [p], load [p^1].
    half8 wzb[2][2], wrb[2][2];
    wzb[0][0] = WFRAG(wz, ct0 + 0, 0);
    wzb[0][1] = WFRAG(wz, ct0 + 1, 0);
    wrb[0][0] = WFRAG(wr, ct0 + 0, 0);
    wrb[0][1] = WFRAG(wr, ct0 + 1, 0);

    // ---- stage x, h -> LDS fp16 (16 outstanding 16B loads/thread) ----
    {
        const float4* xv = reinterpret_cast<const float4*>(x + (size_t)row0 * NHID);
        const float4* hv = reinterpret_cast<const float4*>(h + (size_t)row0 * NHID);
#pragma unroll
        for (int it = 0; it < (MT * 64) / 256; ++it) {
            int i = it * 256 + tid;
            int m = i >> 6;
            int c = (i & 63) * 4;
            float4 a = xv[i];
            float4 b = hv[i];
            half4_t va = { (_Float16)a.x, (_Float16)a.y, (_Float16)a.z, (_Float16)a.w };
            half4_t vb = { (_Float16)b.x, (_Float16)b.y, (_Float16)b.z, (_Float16)b.w };
            *reinterpret_cast<half4_t*>(&lx[lidx(m, c)]) = va;
            *reinterpret_cast<half4_t*>(&lh[lidx(m, c)]) = vb;
        }
    }
    barrier_lgkm();

    // packed (z*h, 1-z) per output element, fp16x2 (16 VGPRs, live pass2 only)
    half2_t zpk[CPW][RT][4];

    // ---- pass 1: Sz = [x|h]@[Wz;Uz], Sr = [x|h]@[Wr;Ur]  (K=512) ----
    // 32 micro-steps (s,p): each = {prefetch next pair's 4 frags, 8 MFMAs}.
    floatx4 accz[CPW][RT];
    floatx4 accr[CPW][RT];
#pragma unroll
    for (int c = 0; c < CPW; ++c)
#pragma unroll
        for (int rt = 0; rt < RT; ++rt) {
            accz[c][rt] = (floatx4){0.f, 0.f, 0.f, 0.f};
            accr[c][rt] = (floatx4){0.f, 0.f, 0.f, 0.f};
        }

#pragma unroll
    for (int s = 0; s < 16; ++s) {
        const _Float16* asrc = (s < 8) ? lx : lh;
        const int kcx = (((s & 7) * 4 + quad) ^ mx) << 3;
        half8 af[RT];
#pragma unroll
        for (int rt = 0; rt < RT; ++rt)
            af[rt] = *reinterpret_cast<const half8*>(&asrc[(rt * 16 + m_lo) * 256 + kcx]);
#pragma unroll
        for (int p = 0; p < 2; ++p) {
            const int u = s * 2 + p;               // micro-step 0..31
            if (u < 31) {
                const int ns = (p == 1) ? s + 1 : s;
                const int nc = ct0 + (p ^ 1) * 2;  // next pair's coltile base
                wzb[p ^ 1][0] = WFRAG(wz, nc + 0, ns);
                wzb[p ^ 1][1] = WFRAG(wz, nc + 1, ns);
                wrb[p ^ 1][0] = WFRAG(wr, nc + 0, ns);
                wrb[p ^ 1][1] = WFRAG(wr, nc + 1, ns);
            }
            __builtin_amdgcn_s_setprio(1);
#pragma unroll
            for (int q = 0; q < 2; ++q) {
                const int c = p * 2 + q;
#pragma unroll
                for (int rt = 0; rt < RT; ++rt) {
                    accz[c][rt] = __builtin_amdgcn_mfma_f32_16x16x32_f16(af[rt], wzb[p][q], accz[c][rt], 0, 0, 0);
                    accr[c][rt] = __builtin_amdgcn_mfma_f32_16x16x32_f16(af[rt], wrb[p][q], accr[c][rt], 0, 0, 0);
                }
            }
            __builtin_amdgcn_s_setprio(0);
        }
    }

    // ---- prefetch pass-2 micro-step-0 weights + all biases: issued before
    //      the barrier, stay in flight through epilogue 1 ----
    half8 whb[2][2];
    whb[0][0] = WFRAG(wh, ct0 + 0, 0);
    whb[0][1] = WFRAG(wh, ct0 + 1, 0);
    float bzv[CPW], brv[CPW], bhv[CPW];
#pragma unroll
    for (int c = 0; c < CPW; ++c) {
        const int col = (ct0 + c) * 16 + m_lo;
        bzv[c] = bz[col];
        brv[c] = br[col];
        bhv[c] = bh[col];
    }

    barrier_lgkm();  // all waves done reading lh (pass 1) before r*h overwrite

    // ---- epilogue 1: z, r; lh <- r*h; zpk <- (fp16)(z*h, 1-z) ----
    // C layout: col(tile) = lane&15, row(tile) = quad*4 + reg
    // NO barrier after this: pass-2 s<8 reads only lx. The lh-visibility
    // barrier sits inside pass 2 at s==8.
#pragma unroll
    for (int c = 0; c < CPW; ++c) {
        const int col = (ct0 + c) * 16 + m_lo;
#pragma unroll
        for (int rt = 0; rt < RT; ++rt) {
#pragma unroll
            for (int e = 0; e < 4; ++e) {
                const int row = rt * 16 + quad * 4 + e;
                float sz = accz[c][rt][e] + bzv[c];
                float sr = accr[c][rt][e] + brv[c];
                float zv = 1.f / (1.f + __expf(-sz));
                float rv = 1.f / (1.f + __expf(-sr));
                const int li = lidx(row, col);
                float hval = (float)lh[li];
                lh[li] = (_Float16)(rv * hval);
                zpk[c][rt][e] = half2_t{ (_Float16)(zv * hval), (_Float16)(1.f - zv) };
            }
        }
    }

    // ---- pass 2: Sh = [x|r*h]@[Wh;Uh]  (K=512), 32 micro-steps ----
    floatx4 acch[CPW][RT];
#pragma unroll
    for (int c = 0; c < CPW; ++c)
#pragma unroll
        for (int rt = 0; rt < RT; ++rt)
            acch[c][rt] = (floatx4){0.f, 0.f, 0.f, 0.f};

#pragma unroll
    for (int s = 0; s < 16; ++s) {
        if (s == 8) barrier_lgkm();  // all epilogue-1 lh (r*h) writes visible
        const _Float16* asrc = (s < 8) ? lx : lh;
        const int kcx = (((s & 7) * 4 + quad) ^ mx) << 3;
        half8 af[RT];
#pragma unroll
        for (int rt = 0; rt < RT; ++rt)
            af[rt] = *reinterpret_cast<const half8*>(&asrc[(rt * 16 + m_lo) * 256 + kcx]);
#pragma unroll
        for (int p = 0; p < 2; ++p) {
            const int u = s * 2 + p;
            if (u < 31) {
                const int ns = (p == 1) ? s + 1 : s;
                const int nc = ct0 + (p ^ 1) * 2;
                whb[p ^ 1][0] = WFRAG(wh, nc + 0, ns);
                whb[p ^ 1][1] = WFRAG(wh, nc + 1, ns);
            }
            __builtin_amdgcn_s_setprio(1);
#pragma unroll
            for (int q = 0; q < 2; ++q) {
                const int c = p * 2 + q;
#pragma unroll
                for (int rt = 0; rt < RT; ++rt)
                    acch[c][rt] = __builtin_amdgcn_mfma_f32_16x16x32_f16(af[rt], whb[p][q], acch[c][rt], 0, 0, 0);
            }
            __builtin_amdgcn_s_setprio(0);
        }
    }

    // ---- epilogue 2: h_t = z*h + (1-z)*tanh(Sh+bh), direct global stores ----
    // No barrier: nothing after this touches LDS. 16-lane groups write
    // contiguous 64 B segments (R5 measured WRITE_SIZE ~= ideal, no
    // amplification).
    const size_t OUT2 = (size_t)B_ROWS * NHID;
#pragma unroll
    for (int c = 0; c < CPW; ++c) {
        const int col = (ct0 + c) * 16 + m_lo;
#pragma unroll
        for (int rt = 0; rt < RT; ++rt) {
#pragma unroll
            for (int e = 0; e < 4; ++e) {
                const int row = rt * 16 + quad * 4 + e;
                float sh = acch[c][rt][e] + bhv[c];
                float e2 = __expf(2.f * sh);
                float hh = 1.f - 2.f / (e2 + 1.f);  // tanh
                float zh  = (float)zpk[c][rt][e][0];
                float omz = (float)zpk[c][rt][e][1];
                float ht  = zh + omz * hh;
                size_t idx = (size_t)(row0 + row) * NHID + col;
                __builtin_nontemporal_store(ht, &out[idx]);
                __builtin_nontemporal_store(ht, &out[OUT2 + idx]);
            }
        }
    }
}

extern "C" void kernel_launch(void* const* d_in, const int* in_sizes, int n_in,
                              void* d_out, int out_size, void* d_ws, size_t ws_size,
                              hipStream_t stream) {
    (void)in_sizes; (void)n_in; (void)out_size; (void)ws_size;
    const float* x  = (const float*)d_in[0];
    const float* h  = (const float*)d_in[1];
    const float* Wz = (const float*)d_in[2];
    const float* Uz = (const float*)d_in[3];
    const float* bz = (const float*)d_in[4];
    const float* Wr = (const float*)d_in[5];
    const float* Ur = (const float*)d_in[6];
    const float* br = (const float*)d_in[7];
    const float* Wh = (const float*)d_in[8];
    const float* Uh = (const float*)d_in[9];
    const float* bh = (const float*)d_in[10];
    float* out = (float*)d_out;
    _Float16* wpack = (_Float16*)d_ws;  // 3*512*256*2 = 768 KB

    pack_weights_kernel<<<192, 256, 0, stream>>>(Wz, Uz, Wr, Ur, Wh, Uh, wpack);
    gru_main_kernel<<<B_ROWS / MT, 256, 0, stream>>>(x, h, wpack, bz, br, bh, out);
}